// Round 8
// baseline (338.187 us; speedup 1.0000x reference)
//
#include <hip/hip_runtime.h>
#include <hip/hip_bf16.h>

#define N_FEAT 64
#define NBW 9                      // log2(nodes per bucket) = 512
#define SRC_BITS 23                // key = (dstLocal << 23) | src ; src < 2^23

typedef unsigned short u16;

__device__ inline u16 f2bf(float f) {           // RNE f32 -> bf16
    unsigned u = __float_as_uint(f);
    u += 0x7fffu + ((u >> 16) & 1u);
    return (u16)(u >> 16);
}

// ---------------- CSR build: two-level bucket partition ----------------

__global__ __launch_bounds__(256) void coarse_hist(const int* __restrict__ ei, int* bcnt, int E, int NB) {
    __shared__ int h[256];
    int tid = threadIdx.x;
    h[tid] = 0;
    __syncthreads();
    for (int e = blockIdx.x * blockDim.x + tid; e < E; e += gridDim.x * blockDim.x)
        atomicAdd(&h[ei[E + e] >> NBW], 1);
    __syncthreads();
    if (tid < NB && h[tid]) atomicAdd(&bcnt[tid], h[tid]);
}

// block 0: exclusive scan of bucket counts; blocks 1..16: pad W3 to 64x64
__global__ __launch_bounds__(256) void scan_pad(const int* __restrict__ bcnt, int* boff, int* bcur, int NB,
                                                const float* __restrict__ W3, float* __restrict__ W3p) {
    if (blockIdx.x == 0) {
        __shared__ int wsum[4];
        int tid = threadIdx.x, lane = tid & 63, w = tid >> 6;
        int v = (tid < NB) ? bcnt[tid] : 0;
        int incl = v;
        #pragma unroll
        for (int o = 1; o < 64; o <<= 1) { int t = __shfl_up(incl, o); if (lane >= o) incl += t; }
        if (lane == 63) wsum[w] = incl;
        __syncthreads();
        int add = 0;
        #pragma unroll
        for (int i = 0; i < 4; ++i) if (i < w) add += wsum[i];
        int excl = add + incl - v;
        if (tid < NB) { boff[tid] = excl; bcur[tid] = excl; }
    } else {
        int i = (blockIdx.x - 1) * 256 + threadIdx.x;
        if (i < 64 * 64) {
            int k = i >> 6, c = i & 63;
            W3p[i] = (c < 16) ? W3[k * 16 + c] : 0.0f;
        }
    }
}

__global__ __launch_bounds__(256) void partition(const int* __restrict__ ei, const float* __restrict__ ew,
                                                 int* bcur, int2* __restrict__ ebuf, int E, int NB) {
    constexpr int EPT = 8;
    __shared__ int cnt[256];
    __shared__ int base[256];
    int tid = threadIdx.x;
    cnt[tid] = 0;
    __syncthreads();
    int start = blockIdx.x * (256 * EPT);

    int d[EPT], r[EPT], s[EPT]; float w[EPT];
    #pragma unroll
    for (int i = 0; i < EPT; ++i) {
        int e = start + i * 256 + tid;
        if (e < E) {
            d[i] = ei[E + e];
            s[i] = ei[e];
            w[i] = ew[e];
            r[i] = atomicAdd(&cnt[d[i] >> NBW], 1);
        } else d[i] = -1;
    }
    __syncthreads();
    if (tid < NB && cnt[tid]) base[tid] = atomicAdd(&bcur[tid], cnt[tid]);
    __syncthreads();
    #pragma unroll
    for (int i = 0; i < EPT; ++i) {
        if (d[i] >= 0) {
            int b = d[i] >> NBW;
            int dl = d[i] & ((1 << NBW) - 1);
            int key = (dl << SRC_BITS) | s[i];
            ebuf[base[b] + r[i]] = make_int2(key, __float_as_int(w[i]));
        }
    }
}

__global__ __launch_bounds__(256) void bucket_csr(const int2* __restrict__ ebuf, const int* __restrict__ boff,
                                                  const int* __restrict__ bcnt,
                                                  int2* __restrict__ csr, int* __restrict__ rowp,
                                                  int* __restrict__ cnt, float* __restrict__ dis, int N) {
    __shared__ int   h[512];
    __shared__ float ws[512];
    __shared__ int   off[512];
    __shared__ int   wsum[4];
    int b = blockIdx.x, tid = threadIdx.x;
    int nbase = b << NBW;
    int nn = min(512, N - nbase);
    int beg = boff[b], m = bcnt[b];

    h[tid] = 0; h[tid + 256] = 0;
    ws[tid] = 0.f; ws[tid + 256] = 0.f;
    __syncthreads();

    for (int i = tid; i < m; i += 256) {
        int2 en = ebuf[beg + i];
        int dl = ((unsigned)en.x) >> SRC_BITS;
        atomicAdd(&h[dl], 1);
        atomicAdd(&ws[dl], __int_as_float(en.y));
    }
    __syncthreads();

    int v0 = h[2 * tid], v1 = h[2 * tid + 1];
    int v = v0 + v1;
    int lane = tid & 63, wv = tid >> 6;
    int incl = v;
    #pragma unroll
    for (int o = 1; o < 64; o <<= 1) { int t = __shfl_up(incl, o); if (lane >= o) incl += t; }
    if (lane == 63) wsum[wv] = incl;
    __syncthreads();
    int add = 0;
    #pragma unroll
    for (int i = 0; i < 4; ++i) if (i < wv) add += wsum[i];
    int excl = add + incl - v;
    off[2 * tid] = excl;
    off[2 * tid + 1] = excl + v0;
    __syncthreads();

    for (int l = tid; l < nn; l += 256) {
        rowp[nbase + l] = beg + off[l];
        cnt[nbase + l]  = h[l];
        dis[nbase + l]  = rsqrtf(1.0f + ws[l]);
    }
    __syncthreads();
    h[tid] = 0; h[tid + 256] = 0;
    __syncthreads();

    for (int i = tid; i < m; i += 256) {
        int2 en = ebuf[beg + i];
        unsigned k = (unsigned)en.x;
        int dl  = k >> SRC_BITS;
        int src = k & ((1 << SRC_BITS) - 1);
        int pos = atomicAdd(&h[dl], 1);
        csr[beg + off[dl] + pos] = make_int2(src, en.y);
    }
}

// fold dis[src] into stored weight
__global__ __launch_bounds__(256) void fold_dis(int2* __restrict__ csr, const float* __restrict__ dis, int E) {
    int i = blockIdx.x * blockDim.x + threadIdx.x;
    if (i < E) {
        int2 en = csr[i];
        en.y = __float_as_int(__int_as_float(en.y) * dis[en.x]);
        csr[i] = en;
    }
}

// ---------------- GEMM: register-resident, LDS-free ----------------
// C_bf16[N x OUTW] = A[N x 64] @ W[64 x 64]; A is f32 or bf16 (INBF).

template<int OUTW, bool INBF>
__global__ __launch_bounds__(256) void gemm_rv(const void* __restrict__ Av, const float* __restrict__ W,
                                               u16* __restrict__ C, int N) {
    int lane = threadIdx.x & 63;
    int wid  = (int)((blockIdx.x * blockDim.x + threadIdx.x) >> 6);
    int nw   = (int)((gridDim.x * blockDim.x) >> 6);

    float wcol[64];
    #pragma unroll
    for (int k = 0; k < 64; ++k) wcol[k] = W[k * 64 + lane];

    for (int r0 = wid * 4; r0 < N; r0 += nw * 4) {
        int rb = __builtin_amdgcn_readfirstlane(r0);     // wave-uniform row base
        float acc0 = 0.f, acc1 = 0.f, acc2 = 0.f, acc3 = 0.f;
        if (INBF) {
            const u16* arow = (const u16*)Av + (size_t)rb * 64;
            for (int kc = 0; kc < 64; kc += 16) {
                #pragma unroll
                for (int kp = 0; kp < 8; ++kp) {
                    int kk = kc + 2 * kp;
                    unsigned p0 = *(const unsigned*)&arow[kk];
                    unsigned p1 = *(const unsigned*)&arow[64 + kk];
                    unsigned p2 = *(const unsigned*)&arow[128 + kk];
                    unsigned p3 = *(const unsigned*)&arow[192 + kk];
                    acc0 = fmaf(__uint_as_float(p0 << 16), wcol[kk], acc0);
                    acc0 = fmaf(__uint_as_float(p0 & 0xffff0000u), wcol[kk + 1], acc0);
                    acc1 = fmaf(__uint_as_float(p1 << 16), wcol[kk], acc1);
                    acc1 = fmaf(__uint_as_float(p1 & 0xffff0000u), wcol[kk + 1], acc1);
                    acc2 = fmaf(__uint_as_float(p2 << 16), wcol[kk], acc2);
                    acc2 = fmaf(__uint_as_float(p2 & 0xffff0000u), wcol[kk + 1], acc2);
                    acc3 = fmaf(__uint_as_float(p3 << 16), wcol[kk], acc3);
                    acc3 = fmaf(__uint_as_float(p3 & 0xffff0000u), wcol[kk + 1], acc3);
                }
            }
        } else {
            const float* arow = (const float*)Av + (size_t)rb * 64;
            for (int kc = 0; kc < 64; kc += 16) {
                #pragma unroll
                for (int k = 0; k < 16; ++k) {
                    int kk = kc + k;
                    acc0 = fmaf(arow[kk],       wcol[kk], acc0);
                    acc1 = fmaf(arow[64 + kk],  wcol[kk], acc1);
                    acc2 = fmaf(arow[128 + kk], wcol[kk], acc2);
                    acc3 = fmaf(arow[192 + kk], wcol[kk], acc3);
                }
            }
        }
        bool cok = (OUTW == 64) || (lane < OUTW);
        if (cok) {
            if (rb + 0 < N) C[(size_t)(rb + 0) * OUTW + lane] = f2bf(acc0);
            if (rb + 1 < N) C[(size_t)(rb + 1) * OUTW + lane] = f2bf(acc1);
            if (rb + 2 < N) C[(size_t)(rb + 2) * OUTW + lane] = f2bf(acc2);
            if (rb + 3 < N) C[(size_t)(rb + 3) * OUTW + lane] = f2bf(acc3);
        }
    }
}

// ---------------- Aggregation (bf16 gathers, direct csr loads, no shuffles) ----
// out[n] = sum_e wf(e)*dd * hw[s] + dd^2*hw[n] + b ; wf = dis[s]*ew (pre-folded)
// FINAL: F=16, writes logits (x2 copies) + fused log-softmax to out0.

template<int F, bool RELU, bool FINAL>
__global__ __launch_bounds__(256) void aggregate(const u16* __restrict__ hw, const int* __restrict__ rowp,
                                                 const int* __restrict__ cnt, const int2* __restrict__ csr,
                                                 const float* __restrict__ dis,
                                                 const float* __restrict__ bias, void* __restrict__ outv,
                                                 float* __restrict__ out2, float* __restrict__ out3, int N) {
    constexpr int LPR = F / 8;        // lanes per row (8 for F=64, 2 for F=16)
    constexpr int EPB = 64 / LPR;     // edge slots in flight (8 or 32)

    int wid = (int)((blockIdx.x * blockDim.x + threadIdx.x) >> 6);
    int lane = threadIdx.x & 63;
    if (wid >= N) return;
    int n = wid;
    int g = lane / LPR;
    int t = lane % LPR;
    float dd = dis[n];

    float acc[8] = {};
    if (g == 0) {                     // self loop (weight 1)
        uint4 raw = *(const uint4*)&hw[(size_t)n * F + t * 8];
        float w = dd * dd;
        unsigned uw[4] = {raw.x, raw.y, raw.z, raw.w};
        #pragma unroll
        for (int k = 0; k < 4; ++k) {
            acc[2 * k]     = w * __uint_as_float(uw[k] << 16);
            acc[2 * k + 1] = w * __uint_as_float(uw[k] & 0xffff0000u);
        }
    }

    int beg = rowp[n];
    int c = cnt[n];
    for (int j0 = 0; j0 < c; j0 += EPB) {
        int idx = j0 + g;
        int ic = min(idx, c - 1);
        int2 ent = csr[beg + ic];            // 8 lanes share one 8B entry (L1 broadcast)
        int s = ent.x;
        float w = (idx < c) ? __int_as_float(ent.y) * dd : 0.0f;
        uint4 raw = *(const uint4*)&hw[(size_t)s * F + t * 8];
        unsigned uw[4] = {raw.x, raw.y, raw.z, raw.w};
        #pragma unroll
        for (int k = 0; k < 4; ++k) {
            acc[2 * k]     = fmaf(w, __uint_as_float(uw[k] << 16), acc[2 * k]);
            acc[2 * k + 1] = fmaf(w, __uint_as_float(uw[k] & 0xffff0000u), acc[2 * k + 1]);
        }
    }

    #pragma unroll
    for (int off = LPR; off < 64; off <<= 1) {
        #pragma unroll
        for (int k = 0; k < 8; ++k) acc[k] += __shfl_xor(acc[k], off);
    }

    if (g == 0) {
        float4 b0 = *(const float4*)&bias[t * 8];
        float4 b1 = *(const float4*)&bias[t * 8 + 4];
        acc[0] += b0.x; acc[1] += b0.y; acc[2] += b0.z; acc[3] += b0.w;
        acc[4] += b1.x; acc[5] += b1.y; acc[6] += b1.z; acc[7] += b1.w;
        if (RELU) {
            #pragma unroll
            for (int k = 0; k < 8; ++k) acc[k] = fmaxf(acc[k], 0.0f);
        }
        if (!FINAL) {
            // bf16 output row (feeds next gemm / gather)
            u16* o16 = (u16*)outv;
            uint4 pk;
            pk.x = (unsigned)f2bf(acc[0]) | ((unsigned)f2bf(acc[1]) << 16);
            pk.y = (unsigned)f2bf(acc[2]) | ((unsigned)f2bf(acc[3]) << 16);
            pk.z = (unsigned)f2bf(acc[4]) | ((unsigned)f2bf(acc[5]) << 16);
            pk.w = (unsigned)f2bf(acc[6]) | ((unsigned)f2bf(acc[7]) << 16);
            *(uint4*)&o16[(size_t)n * F + t * 8] = pk;
        } else {
            // logits (two copies) + fused log-softmax
            float4 r0 = make_float4(acc[0], acc[1], acc[2], acc[3]);
            float4 r1 = make_float4(acc[4], acc[5], acc[6], acc[7]);
            *(float4*)&out2[(size_t)n * F + t * 8] = r0;
            *(float4*)&out2[(size_t)n * F + t * 8 + 4] = r1;
            *(float4*)&out3[(size_t)n * F + t * 8] = r0;
            *(float4*)&out3[(size_t)n * F + t * 8 + 4] = r1;
            float mloc = acc[0];
            #pragma unroll
            for (int k = 1; k < 8; ++k) mloc = fmaxf(mloc, acc[k]);
            float m = fmaxf(mloc, __shfl_xor(mloc, 1));   // lanes 0,1 both active
            float sloc = 0.f;
            #pragma unroll
            for (int k = 0; k < 8; ++k) sloc += __expf(acc[k] - m);
            float ssum = sloc + __shfl_xor(sloc, 1);
            float ls = m + __logf(ssum);
            float* o = (float*)outv;
            float4 w0 = make_float4(acc[0] - ls, acc[1] - ls, acc[2] - ls, acc[3] - ls);
            float4 w1 = make_float4(acc[4] - ls, acc[5] - ls, acc[6] - ls, acc[7] - ls);
            *(float4*)&o[(size_t)n * F + t * 8] = w0;
            *(float4*)&o[(size_t)n * F + t * 8 + 4] = w1;
        }
    }
}

// ---------------- launch ----------------

extern "C" void kernel_launch(void* const* d_in, const int* in_sizes, int n_in,
                              void* d_out, int out_size, void* d_ws, size_t ws_size,
                              hipStream_t stream) {
    const float* x   = (const float*)d_in[0];
    const int*   ei  = (const int*)d_in[1];
    const float* ew  = (const float*)d_in[2];
    const float* W1  = (const float*)d_in[3];
    const float* b1  = (const float*)d_in[4];
    const float* W2  = (const float*)d_in[5];
    const float* b2  = (const float*)d_in[6];
    const float* W3  = (const float*)d_in[7];
    const float* b3  = (const float*)d_in[8];
    float* out = (float*)d_out;

    const int N = in_sizes[0] / N_FEAT;      // 100000
    const int E = in_sizes[2];               // 1600000
    const int NB = (N + (1 << NBW) - 1) >> NBW;

    size_t off = 0;
    auto alloc = [&](size_t bytes) {
        void* p = (char*)d_ws + off;
        off += (bytes + 255) & ~(size_t)255;
        return p;
    };
    float* dis     = (float*)alloc((size_t)N * 4);
    int*   cnt     = (int*)alloc((size_t)N * 4);
    int*   rowp    = (int*)alloc((size_t)N * 4);
    int*   bcnt    = (int*)alloc(256 * 4);
    int*   boff    = (int*)alloc(256 * 4);
    int*   bcur    = (int*)alloc(256 * 4);
    int2*  csr     = (int2*)alloc((size_t)E * 8);
    int2*  ebuf    = (int2*)alloc((size_t)E * 8);
    u16*   bufA16  = (u16*)alloc((size_t)N * 64 * 2);    // bf16 agg output (gemm input)
    u16*   hwB     = (u16*)alloc((size_t)N * 64 * 2);    // bf16 gemm output (gather side)
    u16*   hw16    = (u16*)alloc((size_t)N * 16 * 2);    // bf16 layer-3 gemm output
    float* W3p     = (float*)alloc(64 * 64 * 4);

    const int TB = 256;

    // CSR build
    hipMemsetAsync(bcnt, 0, 256 * 4, stream);
    coarse_hist<<<512, TB, 0, stream>>>(ei, bcnt, E, NB);
    scan_pad<<<17, TB, 0, stream>>>(bcnt, boff, bcur, NB, W3, W3p);
    partition<<<(E + 2047) / 2048, TB, 0, stream>>>(ei, ew, bcur, ebuf, E, NB);
    bucket_csr<<<NB, TB, 0, stream>>>(ebuf, boff, bcnt, csr, rowp, cnt, dis, N);
    fold_dis<<<(E + TB - 1) / TB, TB, 0, stream>>>(csr, dis, E);

    const int GB = 512;
    int ablk = (N * 64 + TB - 1) / TB;

    float* logits = out + (size_t)N * 16;
    float* logits2 = out + (size_t)2 * N * 16;

    // layer 1
    gemm_rv<64, false><<<GB, TB, 0, stream>>>(x, W1, hwB, N);
    aggregate<64, true, false><<<ablk, TB, 0, stream>>>(hwB, rowp, cnt, csr, dis, b1, bufA16, nullptr, nullptr, N);
    // layer 2
    gemm_rv<64, true><<<GB, TB, 0, stream>>>(bufA16, W2, hwB, N);
    aggregate<64, true, false><<<ablk, TB, 0, stream>>>(hwB, rowp, cnt, csr, dis, b2, bufA16, nullptr, nullptr, N);
    // layer 3 + fused log-softmax
    gemm_rv<16, true><<<GB, TB, 0, stream>>>(bufA16, W3p, hw16, N);
    aggregate<16, false, true><<<ablk, TB, 0, stream>>>(hw16, rowp, cnt, csr, dis, b3, out, logits, logits2, N);
}

// Round 9
// 337.147 us; speedup vs baseline: 1.0031x; 1.0031x over previous
//
#include <hip/hip_runtime.h>
#include <hip/hip_bf16.h>

#define N_FEAT 64
#define NBW 9                      // log2(nodes per bucket) = 512
#define SRC_BITS 23                // key = (dstLocal << 23) | src ; src < 2^23

typedef unsigned short u16;

__device__ inline u16 f2bf(float f) {           // RNE f32 -> bf16
    unsigned u = __float_as_uint(f);
    u += 0x7fffu + ((u >> 16) & 1u);
    return (u16)(u >> 16);
}

// ---------------- CSR build: two-level bucket partition ----------------

__global__ __launch_bounds__(256) void coarse_hist(const int* __restrict__ ei, int* bcnt, int E, int NB) {
    __shared__ int h[256];
    int tid = threadIdx.x;
    h[tid] = 0;
    __syncthreads();
    for (int e = blockIdx.x * blockDim.x + tid; e < E; e += gridDim.x * blockDim.x)
        atomicAdd(&h[ei[E + e] >> NBW], 1);
    __syncthreads();
    if (tid < NB && h[tid]) atomicAdd(&bcnt[tid], h[tid]);
}

// block 0: exclusive scan of bucket counts; blocks 1..16: pad W3 to 64x64
__global__ __launch_bounds__(256) void scan_pad(const int* __restrict__ bcnt, int* boff, int* bcur, int NB,
                                                const float* __restrict__ W3, float* __restrict__ W3p) {
    if (blockIdx.x == 0) {
        __shared__ int wsum[4];
        int tid = threadIdx.x, lane = tid & 63, w = tid >> 6;
        int v = (tid < NB) ? bcnt[tid] : 0;
        int incl = v;
        #pragma unroll
        for (int o = 1; o < 64; o <<= 1) { int t = __shfl_up(incl, o); if (lane >= o) incl += t; }
        if (lane == 63) wsum[w] = incl;
        __syncthreads();
        int add = 0;
        #pragma unroll
        for (int i = 0; i < 4; ++i) if (i < w) add += wsum[i];
        int excl = add + incl - v;
        if (tid < NB) { boff[tid] = excl; bcur[tid] = excl; }
    } else {
        int i = (blockIdx.x - 1) * 256 + threadIdx.x;
        if (i < 64 * 64) {
            int k = i >> 6, c = i & 63;
            W3p[i] = (c < 16) ? W3[k * 16 + c] : 0.0f;
        }
    }
}

__global__ __launch_bounds__(256) void partition(const int* __restrict__ ei, const float* __restrict__ ew,
                                                 int* bcur, int2* __restrict__ ebuf, int E, int NB) {
    constexpr int EPT = 8;
    __shared__ int cnt[256];
    __shared__ int base[256];
    int tid = threadIdx.x;
    cnt[tid] = 0;
    __syncthreads();
    int start = blockIdx.x * (256 * EPT);

    int d[EPT], r[EPT], s[EPT]; float w[EPT];
    #pragma unroll
    for (int i = 0; i < EPT; ++i) {
        int e = start + i * 256 + tid;
        if (e < E) {
            d[i] = ei[E + e];
            s[i] = ei[e];
            w[i] = ew[e];
            r[i] = atomicAdd(&cnt[d[i] >> NBW], 1);
        } else d[i] = -1;
    }
    __syncthreads();
    if (tid < NB && cnt[tid]) base[tid] = atomicAdd(&bcur[tid], cnt[tid]);
    __syncthreads();
    #pragma unroll
    for (int i = 0; i < EPT; ++i) {
        if (d[i] >= 0) {
            int b = d[i] >> NBW;
            int dl = d[i] & ((1 << NBW) - 1);
            int key = (dl << SRC_BITS) | s[i];
            ebuf[base[b] + r[i]] = make_int2(key, __float_as_int(w[i]));
        }
    }
}

__global__ __launch_bounds__(256) void bucket_csr(const int2* __restrict__ ebuf, const int* __restrict__ boff,
                                                  const int* __restrict__ bcnt,
                                                  int2* __restrict__ csr, int* __restrict__ rowp,
                                                  int* __restrict__ cnt, float* __restrict__ dis, int N) {
    __shared__ int   h[512];
    __shared__ float ws[512];
    __shared__ int   off[512];
    __shared__ int   wsum[4];
    int b = blockIdx.x, tid = threadIdx.x;
    int nbase = b << NBW;
    int nn = min(512, N - nbase);
    int beg = boff[b], m = bcnt[b];

    h[tid] = 0; h[tid + 256] = 0;
    ws[tid] = 0.f; ws[tid + 256] = 0.f;
    __syncthreads();

    for (int i = tid; i < m; i += 256) {
        int2 en = ebuf[beg + i];
        int dl = ((unsigned)en.x) >> SRC_BITS;
        atomicAdd(&h[dl], 1);
        atomicAdd(&ws[dl], __int_as_float(en.y));
    }
    __syncthreads();

    int v0 = h[2 * tid], v1 = h[2 * tid + 1];
    int v = v0 + v1;
    int lane = tid & 63, wv = tid >> 6;
    int incl = v;
    #pragma unroll
    for (int o = 1; o < 64; o <<= 1) { int t = __shfl_up(incl, o); if (lane >= o) incl += t; }
    if (lane == 63) wsum[wv] = incl;
    __syncthreads();
    int add = 0;
    #pragma unroll
    for (int i = 0; i < 4; ++i) if (i < wv) add += wsum[i];
    int excl = add + incl - v;
    off[2 * tid] = excl;
    off[2 * tid + 1] = excl + v0;
    __syncthreads();

    for (int l = tid; l < nn; l += 256) {
        rowp[nbase + l] = beg + off[l];
        cnt[nbase + l]  = h[l];
        dis[nbase + l]  = rsqrtf(1.0f + ws[l]);
    }
    __syncthreads();
    h[tid] = 0; h[tid + 256] = 0;
    __syncthreads();

    for (int i = tid; i < m; i += 256) {
        int2 en = ebuf[beg + i];
        unsigned k = (unsigned)en.x;
        int dl  = k >> SRC_BITS;
        int src = k & ((1 << SRC_BITS) - 1);
        int pos = atomicAdd(&h[dl], 1);
        csr[beg + off[dl] + pos] = make_int2(src, en.y);
    }
}

// fold dis[src] into stored weight
__global__ __launch_bounds__(256) void fold_dis(int2* __restrict__ csr, const float* __restrict__ dis, int E) {
    int i = blockIdx.x * blockDim.x + threadIdx.x;
    if (i < E) {
        int2 en = csr[i];
        en.y = __float_as_int(__int_as_float(en.y) * dis[en.x]);
        csr[i] = en;
    }
}

// ---------------- GEMM: register-resident, LDS-free ----------------
// C_bf16[N x OUTW] = A[N x 64] @ W[64 x 64]; A is f32 or bf16 (INBF).

template<int OUTW, bool INBF>
__global__ __launch_bounds__(256) void gemm_rv(const void* __restrict__ Av, const float* __restrict__ W,
                                               u16* __restrict__ C, int N) {
    int lane = threadIdx.x & 63;
    int wid  = (int)((blockIdx.x * blockDim.x + threadIdx.x) >> 6);
    int nw   = (int)((gridDim.x * blockDim.x) >> 6);

    float wcol[64];
    #pragma unroll
    for (int k = 0; k < 64; ++k) wcol[k] = W[k * 64 + lane];

    for (int r0 = wid * 4; r0 < N; r0 += nw * 4) {
        int rb = __builtin_amdgcn_readfirstlane(r0);     // wave-uniform row base
        float acc0 = 0.f, acc1 = 0.f, acc2 = 0.f, acc3 = 0.f;
        if (INBF) {
            const u16* arow = (const u16*)Av + (size_t)rb * 64;
            for (int kc = 0; kc < 64; kc += 16) {
                #pragma unroll
                for (int kp = 0; kp < 8; ++kp) {
                    int kk = kc + 2 * kp;
                    unsigned p0 = *(const unsigned*)&arow[kk];
                    unsigned p1 = *(const unsigned*)&arow[64 + kk];
                    unsigned p2 = *(const unsigned*)&arow[128 + kk];
                    unsigned p3 = *(const unsigned*)&arow[192 + kk];
                    acc0 = fmaf(__uint_as_float(p0 << 16), wcol[kk], acc0);
                    acc0 = fmaf(__uint_as_float(p0 & 0xffff0000u), wcol[kk + 1], acc0);
                    acc1 = fmaf(__uint_as_float(p1 << 16), wcol[kk], acc1);
                    acc1 = fmaf(__uint_as_float(p1 & 0xffff0000u), wcol[kk + 1], acc1);
                    acc2 = fmaf(__uint_as_float(p2 << 16), wcol[kk], acc2);
                    acc2 = fmaf(__uint_as_float(p2 & 0xffff0000u), wcol[kk + 1], acc2);
                    acc3 = fmaf(__uint_as_float(p3 << 16), wcol[kk], acc3);
                    acc3 = fmaf(__uint_as_float(p3 & 0xffff0000u), wcol[kk + 1], acc3);
                }
            }
        } else {
            const float* arow = (const float*)Av + (size_t)rb * 64;
            for (int kc = 0; kc < 64; kc += 16) {
                #pragma unroll
                for (int k = 0; k < 16; ++k) {
                    int kk = kc + k;
                    acc0 = fmaf(arow[kk],       wcol[kk], acc0);
                    acc1 = fmaf(arow[64 + kk],  wcol[kk], acc1);
                    acc2 = fmaf(arow[128 + kk], wcol[kk], acc2);
                    acc3 = fmaf(arow[192 + kk], wcol[kk], acc3);
                }
            }
        }
        bool cok = (OUTW == 64) || (lane < OUTW);
        if (cok) {
            if (rb + 0 < N) C[(size_t)(rb + 0) * OUTW + lane] = f2bf(acc0);
            if (rb + 1 < N) C[(size_t)(rb + 1) * OUTW + lane] = f2bf(acc1);
            if (rb + 2 < N) C[(size_t)(rb + 2) * OUTW + lane] = f2bf(acc2);
            if (rb + 3 < N) C[(size_t)(rb + 3) * OUTW + lane] = f2bf(acc3);
        }
    }
}

// ---------------- Aggregation (bf16 gathers, direct csr loads, no shuffles) ----
// out[n] = sum_e wf(e)*dd * hw[s] + dd^2*hw[n] + b ; wf = dis[s]*ew (pre-folded)
// FINAL: F=16, writes logits (x2 copies) + fused log-softmax to out0.

template<int F, bool RELU, bool FINAL>
__global__ __launch_bounds__(256) void aggregate(const u16* __restrict__ hw, const int* __restrict__ rowp,
                                                 const int* __restrict__ cnt, const int2* __restrict__ csr,
                                                 const float* __restrict__ dis,
                                                 const float* __restrict__ bias, void* __restrict__ outv,
                                                 float* __restrict__ out2, float* __restrict__ out3, int N) {
    constexpr int LPR = F / 8;        // lanes per row (8 for F=64, 2 for F=16)
    constexpr int EPB = 64 / LPR;     // edge slots in flight (8 or 32)

    int wid = (int)((blockIdx.x * blockDim.x + threadIdx.x) >> 6);
    int lane = threadIdx.x & 63;
    if (wid >= N) return;
    int n = wid;
    int g = lane / LPR;
    int t = lane % LPR;
    float dd = dis[n];

    float acc[8] = {};
    if (g == 0) {                     // self loop (weight 1)
        uint4 raw = *(const uint4*)&hw[(size_t)n * F + t * 8];
        float w = dd * dd;
        unsigned uw[4] = {raw.x, raw.y, raw.z, raw.w};
        #pragma unroll
        for (int k = 0; k < 4; ++k) {
            acc[2 * k]     = w * __uint_as_float(uw[k] << 16);
            acc[2 * k + 1] = w * __uint_as_float(uw[k] & 0xffff0000u);
        }
    }

    int beg = rowp[n];
    int c = cnt[n];
    for (int j0 = 0; j0 < c; j0 += EPB) {
        int idx = j0 + g;
        int ic = min(idx, c - 1);
        int2 ent = csr[beg + ic];            // 8 lanes share one 8B entry (L1 broadcast)
        int s = ent.x;
        float w = (idx < c) ? __int_as_float(ent.y) * dd : 0.0f;
        uint4 raw = *(const uint4*)&hw[(size_t)s * F + t * 8];
        unsigned uw[4] = {raw.x, raw.y, raw.z, raw.w};
        #pragma unroll
        for (int k = 0; k < 4; ++k) {
            acc[2 * k]     = fmaf(w, __uint_as_float(uw[k] << 16), acc[2 * k]);
            acc[2 * k + 1] = fmaf(w, __uint_as_float(uw[k] & 0xffff0000u), acc[2 * k + 1]);
        }
    }

    #pragma unroll
    for (int off = LPR; off < 64; off <<= 1) {
        #pragma unroll
        for (int k = 0; k < 8; ++k) acc[k] += __shfl_xor(acc[k], off);
    }

    if (g == 0) {
        float4 b0 = *(const float4*)&bias[t * 8];
        float4 b1 = *(const float4*)&bias[t * 8 + 4];
        acc[0] += b0.x; acc[1] += b0.y; acc[2] += b0.z; acc[3] += b0.w;
        acc[4] += b1.x; acc[5] += b1.y; acc[6] += b1.z; acc[7] += b1.w;
        if (RELU) {
            #pragma unroll
            for (int k = 0; k < 8; ++k) acc[k] = fmaxf(acc[k], 0.0f);
        }
        if (!FINAL) {
            // bf16 output row (feeds next gemm / gather)
            u16* o16 = (u16*)outv;
            uint4 pk;
            pk.x = (unsigned)f2bf(acc[0]) | ((unsigned)f2bf(acc[1]) << 16);
            pk.y = (unsigned)f2bf(acc[2]) | ((unsigned)f2bf(acc[3]) << 16);
            pk.z = (unsigned)f2bf(acc[4]) | ((unsigned)f2bf(acc[5]) << 16);
            pk.w = (unsigned)f2bf(acc[6]) | ((unsigned)f2bf(acc[7]) << 16);
            *(uint4*)&o16[(size_t)n * F + t * 8] = pk;
        } else {
            // logits (two copies) + fused log-softmax
            float4 r0 = make_float4(acc[0], acc[1], acc[2], acc[3]);
            float4 r1 = make_float4(acc[4], acc[5], acc[6], acc[7]);
            *(float4*)&out2[(size_t)n * F + t * 8] = r0;
            *(float4*)&out2[(size_t)n * F + t * 8 + 4] = r1;
            *(float4*)&out3[(size_t)n * F + t * 8] = r0;
            *(float4*)&out3[(size_t)n * F + t * 8 + 4] = r1;
            float mloc = acc[0];
            #pragma unroll
            for (int k = 1; k < 8; ++k) mloc = fmaxf(mloc, acc[k]);
            float m = fmaxf(mloc, __shfl_xor(mloc, 1));   // lanes 0,1 both active
            float sloc = 0.f;
            #pragma unroll
            for (int k = 0; k < 8; ++k) sloc += __expf(acc[k] - m);
            float ssum = sloc + __shfl_xor(sloc, 1);
            float ls = m + __logf(ssum);
            float* o = (float*)outv;
            float4 w0 = make_float4(acc[0] - ls, acc[1] - ls, acc[2] - ls, acc[3] - ls);
            float4 w1 = make_float4(acc[4] - ls, acc[5] - ls, acc[6] - ls, acc[7] - ls);
            *(float4*)&o[(size_t)n * F + t * 8] = w0;
            *(float4*)&o[(size_t)n * F + t * 8 + 4] = w1;
        }
    }
}

// ---------------- launch ----------------

extern "C" void kernel_launch(void* const* d_in, const int* in_sizes, int n_in,
                              void* d_out, int out_size, void* d_ws, size_t ws_size,
                              hipStream_t stream) {
    const float* x   = (const float*)d_in[0];
    const int*   ei  = (const int*)d_in[1];
    const float* ew  = (const float*)d_in[2];
    const float* W1  = (const float*)d_in[3];
    const float* b1  = (const float*)d_in[4];
    const float* W2  = (const float*)d_in[5];
    const float* b2  = (const float*)d_in[6];
    const float* W3  = (const float*)d_in[7];
    const float* b3  = (const float*)d_in[8];
    float* out = (float*)d_out;

    const int N = in_sizes[0] / N_FEAT;      // 100000
    const int E = in_sizes[2];               // 1600000
    const int NB = (N + (1 << NBW) - 1) >> NBW;

    size_t off = 0;
    auto alloc = [&](size_t bytes) {
        void* p = (char*)d_ws + off;
        off += (bytes + 255) & ~(size_t)255;
        return p;
    };
    float* dis     = (float*)alloc((size_t)N * 4);
    int*   cnt     = (int*)alloc((size_t)N * 4);
    int*   rowp    = (int*)alloc((size_t)N * 4);
    int*   bcnt    = (int*)alloc(256 * 4);
    int*   boff    = (int*)alloc(256 * 4);
    int*   bcur    = (int*)alloc(256 * 4);
    int2*  csr     = (int2*)alloc((size_t)E * 8);
    int2*  ebuf    = (int2*)alloc((size_t)E * 8);
    u16*   bufA16  = (u16*)alloc((size_t)N * 64 * 2);    // bf16 agg output (gemm input)
    u16*   hwB     = (u16*)alloc((size_t)N * 64 * 2);    // bf16 gemm output (gather side)
    u16*   hw16    = (u16*)alloc((size_t)N * 16 * 2);    // bf16 layer-3 gemm output
    float* W3p     = (float*)alloc(64 * 64 * 4);

    const int TB = 256;

    // CSR build
    hipMemsetAsync(bcnt, 0, 256 * 4, stream);
    coarse_hist<<<512, TB, 0, stream>>>(ei, bcnt, E, NB);
    scan_pad<<<17, TB, 0, stream>>>(bcnt, boff, bcur, NB, W3, W3p);
    partition<<<(E + 2047) / 2048, TB, 0, stream>>>(ei, ew, bcur, ebuf, E, NB);
    bucket_csr<<<NB, TB, 0, stream>>>(ebuf, boff, bcnt, csr, rowp, cnt, dis, N);
    fold_dis<<<(E + TB - 1) / TB, TB, 0, stream>>>(csr, dis, E);

    const int GB = 512;
    int ablk = (N * 64 + TB - 1) / TB;

    float* logits = out + (size_t)N * 16;
    float* logits2 = out + (size_t)2 * N * 16;

    // layer 1
    gemm_rv<64, false><<<GB, TB, 0, stream>>>(x, W1, hwB, N);
    aggregate<64, true, false><<<ablk, TB, 0, stream>>>(hwB, rowp, cnt, csr, dis, b1, bufA16, nullptr, nullptr, N);
    // layer 2
    gemm_rv<64, true><<<GB, TB, 0, stream>>>(bufA16, W2, hwB, N);
    aggregate<64, true, false><<<ablk, TB, 0, stream>>>(hwB, rowp, cnt, csr, dis, b2, bufA16, nullptr, nullptr, N);
    // layer 3 + fused log-softmax
    gemm_rv<16, true><<<GB, TB, 0, stream>>>(bufA16, W3p, hw16, N);
    aggregate<16, false, true><<<ablk, TB, 0, stream>>>(hw16, rowp, cnt, csr, dis, b3, out, logits, logits2, N);
}

// Round 10
// 328.014 us; speedup vs baseline: 1.0310x; 1.0278x over previous
//
#include <hip/hip_runtime.h>
#include <hip/hip_bf16.h>

#define N_FEAT 64
#define NBW 9                      // log2(nodes per bucket) = 512
#define SRC_BITS 23                // key = (dstLocal << 23) | src ; src < 2^23

typedef unsigned short u16;

__device__ inline u16 f2bf(float f) {           // RNE f32 -> bf16
    unsigned u = __float_as_uint(f);
    u += 0x7fffu + ((u >> 16) & 1u);
    return (u16)(u >> 16);
}

// ---------------- CSR build: two-level bucket partition ----------------

__global__ __launch_bounds__(256) void coarse_hist(const int* __restrict__ ei, int* bcnt, int E, int NB) {
    __shared__ int h[256];
    int tid = threadIdx.x;
    h[tid] = 0;
    __syncthreads();
    for (int e = blockIdx.x * blockDim.x + tid; e < E; e += gridDim.x * blockDim.x)
        atomicAdd(&h[ei[E + e] >> NBW], 1);
    __syncthreads();
    if (tid < NB && h[tid]) atomicAdd(&bcnt[tid], h[tid]);
}

// block 0: exclusive scan of bucket counts; blocks 1..16: pad W3 to 64x64
__global__ __launch_bounds__(256) void scan_pad(const int* __restrict__ bcnt, int* boff, int* bcur, int NB,
                                                const float* __restrict__ W3, float* __restrict__ W3p) {
    if (blockIdx.x == 0) {
        __shared__ int wsum[4];
        int tid = threadIdx.x, lane = tid & 63, w = tid >> 6;
        int v = (tid < NB) ? bcnt[tid] : 0;
        int incl = v;
        #pragma unroll
        for (int o = 1; o < 64; o <<= 1) { int t = __shfl_up(incl, o); if (lane >= o) incl += t; }
        if (lane == 63) wsum[w] = incl;
        __syncthreads();
        int add = 0;
        #pragma unroll
        for (int i = 0; i < 4; ++i) if (i < w) add += wsum[i];
        int excl = add + incl - v;
        if (tid < NB) { boff[tid] = excl; bcur[tid] = excl; }
    } else {
        int i = (blockIdx.x - 1) * 256 + threadIdx.x;
        if (i < 64 * 64) {
            int k = i >> 6, c = i & 63;
            W3p[i] = (c < 16) ? W3[k * 16 + c] : 0.0f;
        }
    }
}

__global__ __launch_bounds__(256) void partition(const int* __restrict__ ei, const float* __restrict__ ew,
                                                 int* bcur, int2* __restrict__ ebuf, int E, int NB) {
    constexpr int EPT = 8;
    __shared__ int cnt[256];
    __shared__ int base[256];
    int tid = threadIdx.x;
    cnt[tid] = 0;
    __syncthreads();
    int start = blockIdx.x * (256 * EPT);

    int d[EPT], r[EPT], s[EPT]; float w[EPT];
    #pragma unroll
    for (int i = 0; i < EPT; ++i) {
        int e = start + i * 256 + tid;
        if (e < E) {
            d[i] = ei[E + e];
            s[i] = ei[e];
            w[i] = ew[e];
            r[i] = atomicAdd(&cnt[d[i] >> NBW], 1);
        } else d[i] = -1;
    }
    __syncthreads();
    if (tid < NB && cnt[tid]) base[tid] = atomicAdd(&bcur[tid], cnt[tid]);
    __syncthreads();
    #pragma unroll
    for (int i = 0; i < EPT; ++i) {
        if (d[i] >= 0) {
            int b = d[i] >> NBW;
            int dl = d[i] & ((1 << NBW) - 1);
            int key = (dl << SRC_BITS) | s[i];
            ebuf[base[b] + r[i]] = make_int2(key, __float_as_int(w[i]));
        }
    }
}

__global__ __launch_bounds__(256) void bucket_csr(const int2* __restrict__ ebuf, const int* __restrict__ boff,
                                                  const int* __restrict__ bcnt,
                                                  int2* __restrict__ csr, int* __restrict__ rowp,
                                                  int* __restrict__ cnt, float* __restrict__ dis, int N) {
    __shared__ int   h[512];
    __shared__ float ws[512];
    __shared__ int   off[512];
    __shared__ int   wsum[4];
    int b = blockIdx.x, tid = threadIdx.x;
    int nbase = b << NBW;
    int nn = min(512, N - nbase);
    int beg = boff[b], m = bcnt[b];

    h[tid] = 0; h[tid + 256] = 0;
    ws[tid] = 0.f; ws[tid + 256] = 0.f;
    __syncthreads();

    for (int i = tid; i < m; i += 256) {
        int2 en = ebuf[beg + i];
        int dl = ((unsigned)en.x) >> SRC_BITS;
        atomicAdd(&h[dl], 1);
        atomicAdd(&ws[dl], __int_as_float(en.y));
    }
    __syncthreads();

    int v0 = h[2 * tid], v1 = h[2 * tid + 1];
    int v = v0 + v1;
    int lane = tid & 63, wv = tid >> 6;
    int incl = v;
    #pragma unroll
    for (int o = 1; o < 64; o <<= 1) { int t = __shfl_up(incl, o); if (lane >= o) incl += t; }
    if (lane == 63) wsum[wv] = incl;
    __syncthreads();
    int add = 0;
    #pragma unroll
    for (int i = 0; i < 4; ++i) if (i < wv) add += wsum[i];
    int excl = add + incl - v;
    off[2 * tid] = excl;
    off[2 * tid + 1] = excl + v0;
    __syncthreads();

    for (int l = tid; l < nn; l += 256) {
        rowp[nbase + l] = beg + off[l];
        cnt[nbase + l]  = h[l];
        dis[nbase + l]  = rsqrtf(1.0f + ws[l]);
    }
    __syncthreads();
    h[tid] = 0; h[tid + 256] = 0;
    __syncthreads();

    for (int i = tid; i < m; i += 256) {
        int2 en = ebuf[beg + i];
        unsigned k = (unsigned)en.x;
        int dl  = k >> SRC_BITS;
        int src = k & ((1 << SRC_BITS) - 1);
        int pos = atomicAdd(&h[dl], 1);
        csr[beg + off[dl] + pos] = make_int2(src, en.y);
    }
}

// fold dis[src] into stored weight
__global__ __launch_bounds__(256) void fold_dis(int2* __restrict__ csr, const float* __restrict__ dis, int E) {
    int i = blockIdx.x * blockDim.x + threadIdx.x;
    if (i < E) {
        int2 en = csr[i];
        en.y = __float_as_int(__int_as_float(en.y) * dis[en.x]);
        csr[i] = en;
    }
}

// ---------------- GEMM: register-resident, LDS-free ----------------
// C_bf16[N x OUTW] = A[N x 64] @ W[64 x 64]; A is f32 or bf16 (INBF).

template<int OUTW, bool INBF>
__global__ __launch_bounds__(256) void gemm_rv(const void* __restrict__ Av, const float* __restrict__ W,
                                               u16* __restrict__ C, int N) {
    int lane = threadIdx.x & 63;
    int wid  = (int)((blockIdx.x * blockDim.x + threadIdx.x) >> 6);
    int nw   = (int)((gridDim.x * blockDim.x) >> 6);

    float wcol[64];
    #pragma unroll
    for (int k = 0; k < 64; ++k) wcol[k] = W[k * 64 + lane];

    for (int r0 = wid * 4; r0 < N; r0 += nw * 4) {
        int rb = __builtin_amdgcn_readfirstlane(r0);     // wave-uniform row base
        float acc0 = 0.f, acc1 = 0.f, acc2 = 0.f, acc3 = 0.f;
        if (INBF) {
            const u16* arow = (const u16*)Av + (size_t)rb * 64;
            for (int kc = 0; kc < 64; kc += 16) {
                #pragma unroll
                for (int kp = 0; kp < 8; ++kp) {
                    int kk = kc + 2 * kp;
                    unsigned p0 = *(const unsigned*)&arow[kk];
                    unsigned p1 = *(const unsigned*)&arow[64 + kk];
                    unsigned p2 = *(const unsigned*)&arow[128 + kk];
                    unsigned p3 = *(const unsigned*)&arow[192 + kk];
                    acc0 = fmaf(__uint_as_float(p0 << 16), wcol[kk], acc0);
                    acc0 = fmaf(__uint_as_float(p0 & 0xffff0000u), wcol[kk + 1], acc0);
                    acc1 = fmaf(__uint_as_float(p1 << 16), wcol[kk], acc1);
                    acc1 = fmaf(__uint_as_float(p1 & 0xffff0000u), wcol[kk + 1], acc1);
                    acc2 = fmaf(__uint_as_float(p2 << 16), wcol[kk], acc2);
                    acc2 = fmaf(__uint_as_float(p2 & 0xffff0000u), wcol[kk + 1], acc2);
                    acc3 = fmaf(__uint_as_float(p3 << 16), wcol[kk], acc3);
                    acc3 = fmaf(__uint_as_float(p3 & 0xffff0000u), wcol[kk + 1], acc3);
                }
            }
        } else {
            const float* arow = (const float*)Av + (size_t)rb * 64;
            for (int kc = 0; kc < 64; kc += 16) {
                #pragma unroll
                for (int k = 0; k < 16; ++k) {
                    int kk = kc + k;
                    acc0 = fmaf(arow[kk],       wcol[kk], acc0);
                    acc1 = fmaf(arow[64 + kk],  wcol[kk], acc1);
                    acc2 = fmaf(arow[128 + kk], wcol[kk], acc2);
                    acc3 = fmaf(arow[192 + kk], wcol[kk], acc3);
                }
            }
        }
        bool cok = (OUTW == 64) || (lane < OUTW);
        if (cok) {
            if (rb + 0 < N) C[(size_t)(rb + 0) * OUTW + lane] = f2bf(acc0);
            if (rb + 1 < N) C[(size_t)(rb + 1) * OUTW + lane] = f2bf(acc1);
            if (rb + 2 < N) C[(size_t)(rb + 2) * OUTW + lane] = f2bf(acc2);
            if (rb + 3 < N) C[(size_t)(rb + 3) * OUTW + lane] = f2bf(acc3);
        }
    }
}

// ---------------- Aggregation ----------------
// Batch csr load (1 coalesced int2/lane per 64 edges) + shuffle distribution
// (LDS-latency, not L2) + 2x unrolled slots (2 independent gathers in flight).
// All __shfl executed unconditionally; masking on the RESULT only.
// FINAL: F=16, writes logits (x2 copies) + fused log-softmax.

template<int F, bool RELU, bool FINAL>
__global__ __launch_bounds__(256) void aggregate(const u16* __restrict__ hw, const int* __restrict__ rowp,
                                                 const int* __restrict__ cnt, const int2* __restrict__ csr,
                                                 const float* __restrict__ dis,
                                                 const float* __restrict__ bias, void* __restrict__ outv,
                                                 float* __restrict__ out2, float* __restrict__ out3, int N) {
    constexpr int LPR = F / 8;         // lanes per row (8 for F=64, 2 for F=16)
    constexpr int EPB = 64 / LPR;      // edge slots (8 or 32)
    constexpr unsigned ROWB = F * 2;   // row bytes (128 or 32)

    int wid = (int)((blockIdx.x * blockDim.x + threadIdx.x) >> 6);
    int lane = threadIdx.x & 63;
    if (wid >= N) return;
    int n = wid;
    int g = lane / LPR;
    int t = lane % LPR;
    float dd = dis[n];
    const char* hwb = (const char*)hw;
    unsigned toff = (unsigned)t * 16u;

    float acc[8] = {};
    if (g == 0) {                      // self loop (weight 1)
        uint4 raw = *(const uint4*)(hwb + (unsigned)n * ROWB + toff);
        float w = dd * dd;
        unsigned uw[4] = {raw.x, raw.y, raw.z, raw.w};
        #pragma unroll
        for (int k = 0; k < 4; ++k) {
            acc[2 * k]     = w * __uint_as_float(uw[k] << 16);
            acc[2 * k + 1] = w * __uint_as_float(uw[k] & 0xffff0000u);
        }
    }

    int beg = rowp[n];
    int c = cnt[n];
    for (int base = 0; base < c; base += 64) {
        int m = min(64, c - base);
        int es = 0; float wv = 0.0f;
        if (lane < m) {
            int2 ent = csr[beg + base + lane];     // coalesced batch load
            es = ent.x;
            wv = __int_as_float(ent.y) * dd;       // dis[s] pre-folded
        }
        for (int j = 0; j < m; j += 2 * EPB) {
            int idx0 = j + g;
            int idx1 = j + EPB + g;
            int ic0 = min(idx0, m - 1);
            int ic1 = min(idx1, m - 1);
            int s0 = __shfl(es, ic0);              // unconditional shuffles
            float w0r = __shfl(wv, ic0);
            int s1 = __shfl(es, ic1);
            float w1r = __shfl(wv, ic1);
            float w0 = (idx0 < m) ? w0r : 0.0f;    // mask results only
            float w1 = (idx1 < m) ? w1r : 0.0f;
            uint4 ra = *(const uint4*)(hwb + (unsigned)s0 * ROWB + toff);  // 2 gathers in flight
            uint4 rb = *(const uint4*)(hwb + (unsigned)s1 * ROWB + toff);
            unsigned ua[4] = {ra.x, ra.y, ra.z, ra.w};
            unsigned ub[4] = {rb.x, rb.y, rb.z, rb.w};
            #pragma unroll
            for (int k = 0; k < 4; ++k) {
                acc[2 * k]     = fmaf(w0, __uint_as_float(ua[k] << 16), acc[2 * k]);
                acc[2 * k + 1] = fmaf(w0, __uint_as_float(ua[k] & 0xffff0000u), acc[2 * k + 1]);
            }
            #pragma unroll
            for (int k = 0; k < 4; ++k) {
                acc[2 * k]     = fmaf(w1, __uint_as_float(ub[k] << 16), acc[2 * k]);
                acc[2 * k + 1] = fmaf(w1, __uint_as_float(ub[k] & 0xffff0000u), acc[2 * k + 1]);
            }
        }
    }

    #pragma unroll
    for (int off = LPR; off < 64; off <<= 1) {
        #pragma unroll
        for (int k = 0; k < 8; ++k) acc[k] += __shfl_xor(acc[k], off);
    }

    if (g == 0) {
        float4 b0 = *(const float4*)&bias[t * 8];
        float4 b1 = *(const float4*)&bias[t * 8 + 4];
        acc[0] += b0.x; acc[1] += b0.y; acc[2] += b0.z; acc[3] += b0.w;
        acc[4] += b1.x; acc[5] += b1.y; acc[6] += b1.z; acc[7] += b1.w;
        if (RELU) {
            #pragma unroll
            for (int k = 0; k < 8; ++k) acc[k] = fmaxf(acc[k], 0.0f);
        }
        if (!FINAL) {
            u16* o16 = (u16*)outv;
            uint4 pk;
            pk.x = (unsigned)f2bf(acc[0]) | ((unsigned)f2bf(acc[1]) << 16);
            pk.y = (unsigned)f2bf(acc[2]) | ((unsigned)f2bf(acc[3]) << 16);
            pk.z = (unsigned)f2bf(acc[4]) | ((unsigned)f2bf(acc[5]) << 16);
            pk.w = (unsigned)f2bf(acc[6]) | ((unsigned)f2bf(acc[7]) << 16);
            *(uint4*)&o16[(size_t)n * F + t * 8] = pk;
        } else {
            float4 r0 = make_float4(acc[0], acc[1], acc[2], acc[3]);
            float4 r1 = make_float4(acc[4], acc[5], acc[6], acc[7]);
            *(float4*)&out2[(size_t)n * F + t * 8] = r0;
            *(float4*)&out2[(size_t)n * F + t * 8 + 4] = r1;
            *(float4*)&out3[(size_t)n * F + t * 8] = r0;
            *(float4*)&out3[(size_t)n * F + t * 8 + 4] = r1;
            float mloc = acc[0];
            #pragma unroll
            for (int k = 1; k < 8; ++k) mloc = fmaxf(mloc, acc[k]);
            float m = fmaxf(mloc, __shfl_xor(mloc, 1));   // lanes 0,1 both active
            float sloc = 0.f;
            #pragma unroll
            for (int k = 0; k < 8; ++k) sloc += __expf(acc[k] - m);
            float ssum = sloc + __shfl_xor(sloc, 1);
            float ls = m + __logf(ssum);
            float* o = (float*)outv;
            float4 w0 = make_float4(acc[0] - ls, acc[1] - ls, acc[2] - ls, acc[3] - ls);
            float4 w1 = make_float4(acc[4] - ls, acc[5] - ls, acc[6] - ls, acc[7] - ls);
            *(float4*)&o[(size_t)n * F + t * 8] = w0;
            *(float4*)&o[(size_t)n * F + t * 8 + 4] = w1;
        }
    }
}

// ---------------- launch ----------------

extern "C" void kernel_launch(void* const* d_in, const int* in_sizes, int n_in,
                              void* d_out, int out_size, void* d_ws, size_t ws_size,
                              hipStream_t stream) {
    const float* x   = (const float*)d_in[0];
    const int*   ei  = (const int*)d_in[1];
    const float* ew  = (const float*)d_in[2];
    const float* W1  = (const float*)d_in[3];
    const float* b1  = (const float*)d_in[4];
    const float* W2  = (const float*)d_in[5];
    const float* b2  = (const float*)d_in[6];
    const float* W3  = (const float*)d_in[7];
    const float* b3  = (const float*)d_in[8];
    float* out = (float*)d_out;

    const int N = in_sizes[0] / N_FEAT;      // 100000
    const int E = in_sizes[2];               // 1600000
    const int NB = (N + (1 << NBW) - 1) >> NBW;

    size_t off = 0;
    auto alloc = [&](size_t bytes) {
        void* p = (char*)d_ws + off;
        off += (bytes + 255) & ~(size_t)255;
        return p;
    };
    float* dis     = (float*)alloc((size_t)N * 4);
    int*   cnt     = (int*)alloc((size_t)N * 4);
    int*   rowp    = (int*)alloc((size_t)N * 4);
    int*   bcnt    = (int*)alloc(256 * 4);
    int*   boff    = (int*)alloc(256 * 4);
    int*   bcur    = (int*)alloc(256 * 4);
    int2*  csr     = (int2*)alloc((size_t)E * 8);
    int2*  ebuf    = (int2*)alloc((size_t)E * 8);
    u16*   bufA16  = (u16*)alloc((size_t)N * 64 * 2);    // bf16 agg output (gemm input)
    u16*   hwB     = (u16*)alloc((size_t)N * 64 * 2);    // bf16 gemm output (gather side)
    u16*   hw16    = (u16*)alloc((size_t)N * 16 * 2);    // bf16 layer-3 gemm output
    float* W3p     = (float*)alloc(64 * 64 * 4);

    const int TB = 256;

    // CSR build
    hipMemsetAsync(bcnt, 0, 256 * 4, stream);
    coarse_hist<<<512, TB, 0, stream>>>(ei, bcnt, E, NB);
    scan_pad<<<17, TB, 0, stream>>>(bcnt, boff, bcur, NB, W3, W3p);
    partition<<<(E + 2047) / 2048, TB, 0, stream>>>(ei, ew, bcur, ebuf, E, NB);
    bucket_csr<<<NB, TB, 0, stream>>>(ebuf, boff, bcnt, csr, rowp, cnt, dis, N);
    fold_dis<<<(E + TB - 1) / TB, TB, 0, stream>>>(csr, dis, E);

    const int GB = 512;
    int ablk = (N * 64 + TB - 1) / TB;

    float* logits = out + (size_t)N * 16;
    float* logits2 = out + (size_t)2 * N * 16;

    // layer 1
    gemm_rv<64, false><<<GB, TB, 0, stream>>>(x, W1, hwB, N);
    aggregate<64, true, false><<<ablk, TB, 0, stream>>>(hwB, rowp, cnt, csr, dis, b1, bufA16, nullptr, nullptr, N);
    // layer 2
    gemm_rv<64, true><<<GB, TB, 0, stream>>>(bufA16, W2, hwB, N);
    aggregate<64, true, false><<<ablk, TB, 0, stream>>>(hwB, rowp, cnt, csr, dis, b2, bufA16, nullptr, nullptr, N);
    // layer 3 + fused log-softmax
    gemm_rv<16, true><<<GB, TB, 0, stream>>>(bufA16, W3p, hw16, N);
    aggregate<16, false, true><<<ablk, TB, 0, stream>>>(hw16, rowp, cnt, csr, dis, b3, out, logits, logits2, N);
}

// Round 11
// 268.658 us; speedup vs baseline: 1.2588x; 1.2209x over previous
//
#include <hip/hip_runtime.h>
#include <hip/hip_bf16.h>

#define N_FEAT 64
#define NBW 9                      // log2(nodes per bucket) = 512
#define SRC_BITS 23                // key = (dstLocal << 23) | src ; src < 2^23

typedef unsigned short u16;

__device__ inline u16 f2bf(float f) {           // RNE f32 -> bf16
    unsigned u = __float_as_uint(f);
    u += 0x7fffu + ((u >> 16) & 1u);
    return (u16)(u >> 16);
}

// ---------------- CSR build: two-level bucket partition ----------------

__global__ __launch_bounds__(256) void coarse_hist(const int* __restrict__ ei, int* bcnt, int E, int NB) {
    __shared__ int h[256];
    int tid = threadIdx.x;
    h[tid] = 0;
    __syncthreads();
    for (int e = blockIdx.x * blockDim.x + tid; e < E; e += gridDim.x * blockDim.x)
        atomicAdd(&h[ei[E + e] >> NBW], 1);
    __syncthreads();
    if (tid < NB && h[tid]) atomicAdd(&bcnt[tid], h[tid]);
}

// block 0: exclusive scan of bucket counts; blocks 1..16: pad W3 to 64x64
__global__ __launch_bounds__(256) void scan_pad(const int* __restrict__ bcnt, int* boff, int* bcur, int NB,
                                                const float* __restrict__ W3, float* __restrict__ W3p) {
    if (blockIdx.x == 0) {
        __shared__ int wsum[4];
        int tid = threadIdx.x, lane = tid & 63, w = tid >> 6;
        int v = (tid < NB) ? bcnt[tid] : 0;
        int incl = v;
        #pragma unroll
        for (int o = 1; o < 64; o <<= 1) { int t = __shfl_up(incl, o); if (lane >= o) incl += t; }
        if (lane == 63) wsum[w] = incl;
        __syncthreads();
        int add = 0;
        #pragma unroll
        for (int i = 0; i < 4; ++i) if (i < w) add += wsum[i];
        int excl = add + incl - v;
        if (tid < NB) { boff[tid] = excl; bcur[tid] = excl; }
    } else {
        int i = (blockIdx.x - 1) * 256 + threadIdx.x;
        if (i < 64 * 64) {
            int k = i >> 6, c = i & 63;
            W3p[i] = (c < 16) ? W3[k * 16 + c] : 0.0f;
        }
    }
}

__global__ __launch_bounds__(256) void partition(const int* __restrict__ ei, const float* __restrict__ ew,
                                                 int* bcur, int2* __restrict__ ebuf, int E, int NB) {
    constexpr int EPT = 8;
    __shared__ int cnt[256];
    __shared__ int base[256];
    int tid = threadIdx.x;
    cnt[tid] = 0;
    __syncthreads();
    int start = blockIdx.x * (256 * EPT);

    int d[EPT], r[EPT], s[EPT]; float w[EPT];
    #pragma unroll
    for (int i = 0; i < EPT; ++i) {
        int e = start + i * 256 + tid;
        if (e < E) {
            d[i] = ei[E + e];
            s[i] = ei[e];
            w[i] = ew[e];
            r[i] = atomicAdd(&cnt[d[i] >> NBW], 1);
        } else d[i] = -1;
    }
    __syncthreads();
    if (tid < NB && cnt[tid]) base[tid] = atomicAdd(&bcur[tid], cnt[tid]);
    __syncthreads();
    #pragma unroll
    for (int i = 0; i < EPT; ++i) {
        if (d[i] >= 0) {
            int b = d[i] >> NBW;
            int dl = d[i] & ((1 << NBW) - 1);
            int key = (dl << SRC_BITS) | s[i];
            ebuf[base[b] + r[i]] = make_int2(key, __float_as_int(w[i]));
        }
    }
}

__global__ __launch_bounds__(256) void bucket_csr(const int2* __restrict__ ebuf, const int* __restrict__ boff,
                                                  const int* __restrict__ bcnt,
                                                  int2* __restrict__ csr, int* __restrict__ rowp,
                                                  int* __restrict__ cnt, float* __restrict__ dis, int N) {
    __shared__ int   h[512];
    __shared__ float ws[512];
    __shared__ int   off[512];
    __shared__ int   wsum[4];
    int b = blockIdx.x, tid = threadIdx.x;
    int nbase = b << NBW;
    int nn = min(512, N - nbase);
    int beg = boff[b], m = bcnt[b];

    h[tid] = 0; h[tid + 256] = 0;
    ws[tid] = 0.f; ws[tid + 256] = 0.f;
    __syncthreads();

    for (int i = tid; i < m; i += 256) {
        int2 en = ebuf[beg + i];
        int dl = ((unsigned)en.x) >> SRC_BITS;
        atomicAdd(&h[dl], 1);
        atomicAdd(&ws[dl], __int_as_float(en.y));
    }
    __syncthreads();

    int v0 = h[2 * tid], v1 = h[2 * tid + 1];
    int v = v0 + v1;
    int lane = tid & 63, wv = tid >> 6;
    int incl = v;
    #pragma unroll
    for (int o = 1; o < 64; o <<= 1) { int t = __shfl_up(incl, o); if (lane >= o) incl += t; }
    if (lane == 63) wsum[wv] = incl;
    __syncthreads();
    int add = 0;
    #pragma unroll
    for (int i = 0; i < 4; ++i) if (i < wv) add += wsum[i];
    int excl = add + incl - v;
    off[2 * tid] = excl;
    off[2 * tid + 1] = excl + v0;
    __syncthreads();

    for (int l = tid; l < nn; l += 256) {
        rowp[nbase + l] = beg + off[l];
        cnt[nbase + l]  = h[l];
        dis[nbase + l]  = rsqrtf(1.0f + ws[l]);
    }
    __syncthreads();
    h[tid] = 0; h[tid + 256] = 0;
    __syncthreads();

    for (int i = tid; i < m; i += 256) {
        int2 en = ebuf[beg + i];
        unsigned k = (unsigned)en.x;
        int dl  = k >> SRC_BITS;
        int src = k & ((1 << SRC_BITS) - 1);
        int pos = atomicAdd(&h[dl], 1);
        csr[beg + off[dl] + pos] = make_int2(src, en.y);
    }
}

// fold dis[src] into stored weight
__global__ __launch_bounds__(256) void fold_dis(int2* __restrict__ csr, const float* __restrict__ dis, int E) {
    int i = blockIdx.x * blockDim.x + threadIdx.x;
    if (i < E) {
        int2 en = csr[i];
        en.y = __float_as_int(__int_as_float(en.y) * dis[en.x]);
        csr[i] = en;
    }
}

// ---------------- GEMM: register-resident, LDS-free ----------------
// C_bf16[N x OUTW] = A[N x 64] @ W[64 x 64]; A is f32 or bf16 (INBF).

template<int OUTW, bool INBF>
__global__ __launch_bounds__(256) void gemm_rv(const void* __restrict__ Av, const float* __restrict__ W,
                                               u16* __restrict__ C, int N) {
    int lane = threadIdx.x & 63;
    int wid  = (int)((blockIdx.x * blockDim.x + threadIdx.x) >> 6);
    int nw   = (int)((gridDim.x * blockDim.x) >> 6);

    float wcol[64];
    #pragma unroll
    for (int k = 0; k < 64; ++k) wcol[k] = W[k * 64 + lane];

    for (int r0 = wid * 4; r0 < N; r0 += nw * 4) {
        int rb = __builtin_amdgcn_readfirstlane(r0);     // wave-uniform row base
        float acc0 = 0.f, acc1 = 0.f, acc2 = 0.f, acc3 = 0.f;
        if (INBF) {
            const u16* arow = (const u16*)Av + (size_t)rb * 64;
            for (int kc = 0; kc < 64; kc += 16) {
                #pragma unroll
                for (int kp = 0; kp < 8; ++kp) {
                    int kk = kc + 2 * kp;
                    unsigned p0 = *(const unsigned*)&arow[kk];
                    unsigned p1 = *(const unsigned*)&arow[64 + kk];
                    unsigned p2 = *(const unsigned*)&arow[128 + kk];
                    unsigned p3 = *(const unsigned*)&arow[192 + kk];
                    acc0 = fmaf(__uint_as_float(p0 << 16), wcol[kk], acc0);
                    acc0 = fmaf(__uint_as_float(p0 & 0xffff0000u), wcol[kk + 1], acc0);
                    acc1 = fmaf(__uint_as_float(p1 << 16), wcol[kk], acc1);
                    acc1 = fmaf(__uint_as_float(p1 & 0xffff0000u), wcol[kk + 1], acc1);
                    acc2 = fmaf(__uint_as_float(p2 << 16), wcol[kk], acc2);
                    acc2 = fmaf(__uint_as_float(p2 & 0xffff0000u), wcol[kk + 1], acc2);
                    acc3 = fmaf(__uint_as_float(p3 << 16), wcol[kk], acc3);
                    acc3 = fmaf(__uint_as_float(p3 & 0xffff0000u), wcol[kk + 1], acc3);
                }
            }
        } else {
            const float* arow = (const float*)Av + (size_t)rb * 64;
            for (int kc = 0; kc < 64; kc += 16) {
                #pragma unroll
                for (int k = 0; k < 16; ++k) {
                    int kk = kc + k;
                    acc0 = fmaf(arow[kk],       wcol[kk], acc0);
                    acc1 = fmaf(arow[64 + kk],  wcol[kk], acc1);
                    acc2 = fmaf(arow[128 + kk], wcol[kk], acc2);
                    acc3 = fmaf(arow[192 + kk], wcol[kk], acc3);
                }
            }
        }
        bool cok = (OUTW == 64) || (lane < OUTW);
        if (cok) {
            if (rb + 0 < N) C[(size_t)(rb + 0) * OUTW + lane] = f2bf(acc0);
            if (rb + 1 < N) C[(size_t)(rb + 1) * OUTW + lane] = f2bf(acc1);
            if (rb + 2 < N) C[(size_t)(rb + 2) * OUTW + lane] = f2bf(acc2);
            if (rb + 3 < N) C[(size_t)(rb + 3) * OUTW + lane] = f2bf(acc3);
        }
    }
}

// ---------------- Aggregation: one node per 8-lane GROUP (shuffle-free) ------
// Wave = (64/GL) groups; group g owns node wid*NPW+g entirely. The group's GL
// lanes read the SAME csr entry (8B broadcast, no bpermute) and gather their
// 16B row slice. No cross-group reduce: each lane owns its 8 output features.
// Divergence across groups (different degrees) is handled by the exec mask.
// FINAL: F=16 (GL=2), logits x2 + fused log-softmax (one shfl_xor pair).

template<int F, bool RELU, bool FINAL>
__global__ __launch_bounds__(256) void aggregate(const u16* __restrict__ hw, const int* __restrict__ rowp,
                                                 const int* __restrict__ cnt, const int2* __restrict__ csr,
                                                 const float* __restrict__ dis,
                                                 const float* __restrict__ bias, void* __restrict__ outv,
                                                 float* __restrict__ out2, float* __restrict__ out3, int N) {
    constexpr int GL   = F / 8;          // lanes per group/node (8 for F=64, 2 for F=16)
    constexpr int NPW  = 64 / GL;        // nodes per wave (8 or 32)
    constexpr unsigned ROWB = F * 2;     // row bytes (128 or 32)

    int wv   = (int)((blockIdx.x * blockDim.x + threadIdx.x) >> 6);
    int lane = threadIdx.x & 63;
    int g = lane / GL;
    int t = lane % GL;
    int n = wv * NPW + g;
    bool alive = (n < N);
    n = min(n, N - 1);

    float dd = dis[n];
    int beg = rowp[n];
    int c   = cnt[n];
    const char* hwb = (const char*)hw;
    unsigned toff = (unsigned)t * 16u;

    float acc[8];
    {   // self loop (weight 1)
        uint4 raw = *(const uint4*)(hwb + (unsigned)n * ROWB + toff);
        float w = dd * dd;
        unsigned uw[4] = {raw.x, raw.y, raw.z, raw.w};
        #pragma unroll
        for (int k = 0; k < 4; ++k) {
            acc[2 * k]     = w * __uint_as_float(uw[k] << 16);
            acc[2 * k + 1] = w * __uint_as_float(uw[k] & 0xffff0000u);
        }
    }

    int j = 0;
    for (; j + 4 <= c; j += 4) {         // 4 independent gathers in flight
        int2 e0 = csr[beg + j];
        int2 e1 = csr[beg + j + 1];
        int2 e2 = csr[beg + j + 2];
        int2 e3 = csr[beg + j + 3];
        uint4 r0 = *(const uint4*)(hwb + (unsigned)e0.x * ROWB + toff);
        uint4 r1 = *(const uint4*)(hwb + (unsigned)e1.x * ROWB + toff);
        uint4 r2 = *(const uint4*)(hwb + (unsigned)e2.x * ROWB + toff);
        uint4 r3 = *(const uint4*)(hwb + (unsigned)e3.x * ROWB + toff);
        float w0 = __int_as_float(e0.y) * dd;
        float w1 = __int_as_float(e1.y) * dd;
        float w2 = __int_as_float(e2.y) * dd;
        float w3 = __int_as_float(e3.y) * dd;
        unsigned ua[4] = {r0.x, r0.y, r0.z, r0.w};
        unsigned ub[4] = {r1.x, r1.y, r1.z, r1.w};
        unsigned uc[4] = {r2.x, r2.y, r2.z, r2.w};
        unsigned ud[4] = {r3.x, r3.y, r3.z, r3.w};
        #pragma unroll
        for (int k = 0; k < 4; ++k) {
            acc[2 * k]     = fmaf(w0, __uint_as_float(ua[k] << 16), acc[2 * k]);
            acc[2 * k + 1] = fmaf(w0, __uint_as_float(ua[k] & 0xffff0000u), acc[2 * k + 1]);
            acc[2 * k]     = fmaf(w1, __uint_as_float(ub[k] << 16), acc[2 * k]);
            acc[2 * k + 1] = fmaf(w1, __uint_as_float(ub[k] & 0xffff0000u), acc[2 * k + 1]);
            acc[2 * k]     = fmaf(w2, __uint_as_float(uc[k] << 16), acc[2 * k]);
            acc[2 * k + 1] = fmaf(w2, __uint_as_float(uc[k] & 0xffff0000u), acc[2 * k + 1]);
            acc[2 * k]     = fmaf(w3, __uint_as_float(ud[k] << 16), acc[2 * k]);
            acc[2 * k + 1] = fmaf(w3, __uint_as_float(ud[k] & 0xffff0000u), acc[2 * k + 1]);
        }
    }
    for (; j < c; ++j) {                 // tail (<=3)
        int2 e = csr[beg + j];
        uint4 r = *(const uint4*)(hwb + (unsigned)e.x * ROWB + toff);
        float w = __int_as_float(e.y) * dd;
        unsigned u[4] = {r.x, r.y, r.z, r.w};
        #pragma unroll
        for (int k = 0; k < 4; ++k) {
            acc[2 * k]     = fmaf(w, __uint_as_float(u[k] << 16), acc[2 * k]);
            acc[2 * k + 1] = fmaf(w, __uint_as_float(u[k] & 0xffff0000u), acc[2 * k + 1]);
        }
    }

    if (alive) {
        float4 b0 = *(const float4*)&bias[t * 8];
        float4 b1 = *(const float4*)&bias[t * 8 + 4];
        acc[0] += b0.x; acc[1] += b0.y; acc[2] += b0.z; acc[3] += b0.w;
        acc[4] += b1.x; acc[5] += b1.y; acc[6] += b1.z; acc[7] += b1.w;
        if (RELU) {
            #pragma unroll
            for (int k = 0; k < 8; ++k) acc[k] = fmaxf(acc[k], 0.0f);
        }
        if (!FINAL) {
            u16* o16 = (u16*)outv;
            uint4 pk;
            pk.x = (unsigned)f2bf(acc[0]) | ((unsigned)f2bf(acc[1]) << 16);
            pk.y = (unsigned)f2bf(acc[2]) | ((unsigned)f2bf(acc[3]) << 16);
            pk.z = (unsigned)f2bf(acc[4]) | ((unsigned)f2bf(acc[5]) << 16);
            pk.w = (unsigned)f2bf(acc[6]) | ((unsigned)f2bf(acc[7]) << 16);
            *(uint4*)&o16[(size_t)n * F + t * 8] = pk;
        } else {
            float4 r0 = make_float4(acc[0], acc[1], acc[2], acc[3]);
            float4 r1 = make_float4(acc[4], acc[5], acc[6], acc[7]);
            *(float4*)&out2[(size_t)n * F + t * 8] = r0;
            *(float4*)&out2[(size_t)n * F + t * 8 + 4] = r1;
            *(float4*)&out3[(size_t)n * F + t * 8] = r0;
            *(float4*)&out3[(size_t)n * F + t * 8 + 4] = r1;
            float mloc = acc[0];
            #pragma unroll
            for (int k = 1; k < 8; ++k) mloc = fmaxf(mloc, acc[k]);
            float m = fmaxf(mloc, __shfl_xor(mloc, 1));   // partner lane same group, same alive
            float sloc = 0.f;
            #pragma unroll
            for (int k = 0; k < 8; ++k) sloc += __expf(acc[k] - m);
            float ssum = sloc + __shfl_xor(sloc, 1);
            float ls = m + __logf(ssum);
            float* o = (float*)outv;
            float4 w0 = make_float4(acc[0] - ls, acc[1] - ls, acc[2] - ls, acc[3] - ls);
            float4 w1 = make_float4(acc[4] - ls, acc[5] - ls, acc[6] - ls, acc[7] - ls);
            *(float4*)&o[(size_t)n * F + t * 8] = w0;
            *(float4*)&o[(size_t)n * F + t * 8 + 4] = w1;
        }
    }
}

// ---------------- launch ----------------

extern "C" void kernel_launch(void* const* d_in, const int* in_sizes, int n_in,
                              void* d_out, int out_size, void* d_ws, size_t ws_size,
                              hipStream_t stream) {
    const float* x   = (const float*)d_in[0];
    const int*   ei  = (const int*)d_in[1];
    const float* ew  = (const float*)d_in[2];
    const float* W1  = (const float*)d_in[3];
    const float* b1  = (const float*)d_in[4];
    const float* W2  = (const float*)d_in[5];
    const float* b2  = (const float*)d_in[6];
    const float* W3  = (const float*)d_in[7];
    const float* b3  = (const float*)d_in[8];
    float* out = (float*)d_out;

    const int N = in_sizes[0] / N_FEAT;      // 100000
    const int E = in_sizes[2];               // 1600000
    const int NB = (N + (1 << NBW) - 1) >> NBW;

    size_t off = 0;
    auto alloc = [&](size_t bytes) {
        void* p = (char*)d_ws + off;
        off += (bytes + 255) & ~(size_t)255;
        return p;
    };
    float* dis     = (float*)alloc((size_t)N * 4);
    int*   cnt     = (int*)alloc((size_t)N * 4);
    int*   rowp    = (int*)alloc((size_t)N * 4);
    int*   bcnt    = (int*)alloc(256 * 4);
    int*   boff    = (int*)alloc(256 * 4);
    int*   bcur    = (int*)alloc(256 * 4);
    int2*  csr     = (int2*)alloc((size_t)E * 8);
    int2*  ebuf    = (int2*)alloc((size_t)E * 8);
    u16*   bufA16  = (u16*)alloc((size_t)N * 64 * 2);    // bf16 agg output (gemm input)
    u16*   hwB     = (u16*)alloc((size_t)N * 64 * 2);    // bf16 gemm output (gather side)
    u16*   hw16    = (u16*)alloc((size_t)N * 16 * 2);    // bf16 layer-3 gemm output
    float* W3p     = (float*)alloc(64 * 64 * 4);

    const int TB = 256;

    // CSR build
    hipMemsetAsync(bcnt, 0, 256 * 4, stream);
    coarse_hist<<<512, TB, 0, stream>>>(ei, bcnt, E, NB);
    scan_pad<<<17, TB, 0, stream>>>(bcnt, boff, bcur, NB, W3, W3p);
    partition<<<(E + 2047) / 2048, TB, 0, stream>>>(ei, ew, bcur, ebuf, E, NB);
    bucket_csr<<<NB, TB, 0, stream>>>(ebuf, boff, bcnt, csr, rowp, cnt, dis, N);
    fold_dis<<<(E + TB - 1) / TB, TB, 0, stream>>>(csr, dis, E);

    const int GB = 512;
    int ablk64 = (N * 8 + TB - 1) / TB;      // 8 lanes/node
    int ablk16 = (N * 2 + TB - 1) / TB;      // 2 lanes/node

    float* logits = out + (size_t)N * 16;
    float* logits2 = out + (size_t)2 * N * 16;

    // layer 1
    gemm_rv<64, false><<<GB, TB, 0, stream>>>(x, W1, hwB, N);
    aggregate<64, true, false><<<ablk64, TB, 0, stream>>>(hwB, rowp, cnt, csr, dis, b1, bufA16, nullptr, nullptr, N);
    // layer 2
    gemm_rv<64, true><<<GB, TB, 0, stream>>>(bufA16, W2, hwB, N);
    aggregate<64, true, false><<<ablk64, TB, 0, stream>>>(hwB, rowp, cnt, csr, dis, b2, bufA16, nullptr, nullptr, N);
    // layer 3 + fused log-softmax
    gemm_rv<16, true><<<GB, TB, 0, stream>>>(bufA16, W3p, hw16, N);
    aggregate<16, false, true><<<ablk16, TB, 0, stream>>>(hw16, rowp, cnt, csr, dis, b3, out, logits, logits2, N);
}